// Round 1
// baseline (1343.155 us; speedup 1.0000x reference)
//
#include <hip/hip_runtime.h>

// ---------------------------------------------------------------------------
// LoRA QKV: out_p = x @ (W_p + B_p @ A_p)^T  for p in {q,k,v}
// M = 4*2048 = 8192, N = H = 4096, K = D = 4096, R = 16
// Strategy: fold LoRA into weights (exact), convert to bf16, 3 GEMMs via MFMA.
// ---------------------------------------------------------------------------

typedef __bf16 bf16x8 __attribute__((ext_vector_type(8)));
typedef float f32x4 __attribute__((ext_vector_type(4)));

#define GLL16(g, l)                                                        \
  __builtin_amdgcn_global_load_lds(                                        \
      (const __attribute__((address_space(1))) unsigned int*)(g),          \
      (__attribute__((address_space(3))) unsigned int*)(l), 16, 0, 0)

// fp32 -> bf16 round-to-nearest-even (bit-level, no NaN special-casing:
// inputs are well-scaled gaussians)
__device__ __forceinline__ unsigned int f2b(float f) {
  unsigned int u = __builtin_bit_cast(unsigned int, f);
  u += 0x7FFFu + ((u >> 16) & 1u);
  return u >> 16;  // low 16 bits hold the bf16
}

// ---------------------------------------------------------------------------
// Kernel 1: convert x (fp32) -> bf16, vectorized 8 elems/thread
// ---------------------------------------------------------------------------
__global__ void cvt_x_kernel(const float* __restrict__ x,
                             unsigned short* __restrict__ xb, long n8) {
  long i = (long)blockIdx.x * blockDim.x + threadIdx.x;
  if (i >= n8) return;
  const float4* xp = reinterpret_cast<const float4*>(x) + 2 * i;
  float4 v0 = xp[0];
  float4 v1 = xp[1];
  uint4 o;
  o.x = f2b(v0.x) | (f2b(v0.y) << 16);
  o.y = f2b(v0.z) | (f2b(v0.w) << 16);
  o.z = f2b(v1.x) | (f2b(v1.y) << 16);
  o.w = f2b(v1.z) | (f2b(v1.w) << 16);
  reinterpret_cast<uint4*>(xb)[i] = o;
}

// ---------------------------------------------------------------------------
// Kernel 2: W' = W + Bm @ A  (rank-16 update), fp32 accum, bf16 out.
// One projection per launch. 8 consecutive d per thread; h uniform per block.
// ---------------------------------------------------------------------------
__global__ void fold_w_kernel(const float* __restrict__ W,
                              const float* __restrict__ Amat,
                              const float* __restrict__ Bmat,
                              unsigned short* __restrict__ Wb) {
  int g = blockIdx.x * 256 + threadIdx.x;  // < 2,097,152
  int d0 = (g & 511) * 8;                  // D/8 = 512 chunks per row
  int h = g >> 9;
  const float4* wp = reinterpret_cast<const float4*>(W + (size_t)h * 4096 + d0);
  float4 w0 = wp[0], w1 = wp[1];
  float acc[8] = {w0.x, w0.y, w0.z, w0.w, w1.x, w1.y, w1.z, w1.w};
  const float* bh = Bmat + h * 16;  // uniform within block -> scalar loads
#pragma unroll
  for (int r = 0; r < 16; ++r) {
    float bv = bh[r];
    const float4* ap =
        reinterpret_cast<const float4*>(Amat + (size_t)r * 4096 + d0);
    float4 a0 = ap[0], a1 = ap[1];
    acc[0] += bv * a0.x; acc[1] += bv * a0.y;
    acc[2] += bv * a0.z; acc[3] += bv * a0.w;
    acc[4] += bv * a1.x; acc[5] += bv * a1.y;
    acc[6] += bv * a1.z; acc[7] += bv * a1.w;
  }
  uint4 o;
  o.x = f2b(acc[0]) | (f2b(acc[1]) << 16);
  o.y = f2b(acc[2]) | (f2b(acc[3]) << 16);
  o.z = f2b(acc[4]) | (f2b(acc[5]) << 16);
  o.w = f2b(acc[6]) | (f2b(acc[7]) << 16);
  reinterpret_cast<uint4*>(Wb)[g] = o;
}

// ---------------------------------------------------------------------------
// Kernel 3: GEMM  C[M,N] = Xb[M,K] @ Wb[N,K]^T   (both K-major, bf16 -> fp32)
// 128x128 tile, BK=32, 256 threads (4 waves, 2x2), mfma_f32_16x16x32_bf16.
// m97-style: global_load_lds width-16 staging, 2 barriers per K-step.
// Grid = 64 (brow) * 32 (bcol) * 3 (proj) = 6144, XCD-swizzled (6144%8==0).
// ---------------------------------------------------------------------------
__global__ __launch_bounds__(256, 2) void gemm_kernel(
    const unsigned short* __restrict__ Xb, const unsigned short* __restrict__ Wb,
    float* __restrict__ out) {
  __shared__ unsigned short As[128 * 32];
  __shared__ unsigned short Bs[128 * 32];

  int bid = blockIdx.x;
  // bijective XCD swizzle: 6144 wgs / 8 XCDs = 768 per XCD
  int swz = (bid & 7) * 768 + (bid >> 3);
  int p = swz >> 11;     // projection 0..2
  int t = swz & 2047;
  int brow = t >> 5;     // 0..63
  int bcol = t & 31;     // 0..31

  const unsigned short* Wp = Wb + (size_t)p * (4096UL * 4096UL);

  int tid = threadIdx.x;
  int lane = tid & 63;
  int wid = tid >> 6;
  int wr = wid >> 1;  // wave row 0..1
  int wc = wid & 1;   // wave col 0..1

  // staging addresses: thread t covers 8 bf16 = 16B; 4 threads per 32-elem row
  const unsigned short* pa0 =
      Xb + ((size_t)(brow * 128 + (tid >> 2))) * 4096 + (tid & 3) * 8;
  const unsigned short* pb0 =
      Wp + ((size_t)(bcol * 128 + (tid >> 2))) * 4096 + (tid & 3) * 8;
  unsigned short* la0 = As + tid * 8;
  unsigned short* lb0 = Bs + tid * 8;

  f32x4 zero = {0.f, 0.f, 0.f, 0.f};
  f32x4 acc[4][4];
#pragma unroll
  for (int m = 0; m < 4; ++m)
#pragma unroll
    for (int n = 0; n < 4; ++n) acc[m][n] = zero;

  // fragment read base: row = (wave row base + lane%16), k-slot = (lane/16)*8
  const unsigned short* ar = As + (wr * 64 + (lane & 15)) * 32 + (lane >> 4) * 8;
  const unsigned short* br = Bs + (wc * 64 + (lane & 15)) * 32 + (lane >> 4) * 8;

  for (int kt = 0; kt < 128; ++kt) {
    const unsigned short* ga = pa0 + kt * 32;
    const unsigned short* gb = pb0 + kt * 32;
    GLL16(ga, la0);
    GLL16(ga + 64 * 4096, la0 + 2048);
    GLL16(gb, lb0);
    GLL16(gb + 64 * 4096, lb0 + 2048);
    __syncthreads();  // drains vmcnt -> LDS tiles ready

    bf16x8 a[4], b[4];
#pragma unroll
    for (int m = 0; m < 4; ++m)
      a[m] = *reinterpret_cast<const bf16x8*>(ar + m * 16 * 32);
#pragma unroll
    for (int n = 0; n < 4; ++n)
      b[n] = *reinterpret_cast<const bf16x8*>(br + n * 16 * 32);

#pragma unroll
    for (int m = 0; m < 4; ++m)
#pragma unroll
      for (int n = 0; n < 4; ++n)
        acc[m][n] =
            __builtin_amdgcn_mfma_f32_16x16x32_bf16(a[m], b[n], acc[m][n], 0, 0, 0);
    __syncthreads();  // all reads done before next stage overwrites
  }

  // epilogue: C/D layout col = lane&15, row = (lane>>4)*4 + q  [m89-verified]
  float* Cp = out + (size_t)p * (8192UL * 4096UL);
  int crow = brow * 128 + wr * 64 + ((lane >> 4) << 2);
  int ccol = bcol * 128 + wc * 64 + (lane & 15);
  float* cb = Cp + (size_t)crow * 4096 + ccol;
#pragma unroll
  for (int m = 0; m < 4; ++m)
#pragma unroll
    for (int q = 0; q < 4; ++q) {
      float* row = cb + (size_t)(m * 16 + q) * 4096;
#pragma unroll
      for (int n = 0; n < 4; ++n) row[n * 16] = acc[m][n][q];
    }
}

// ---------------------------------------------------------------------------
extern "C" void kernel_launch(void* const* d_in, const int* in_sizes, int n_in,
                              void* d_out, int out_size, void* d_ws,
                              size_t ws_size, hipStream_t stream) {
  const float* x = (const float*)d_in[0];
  const float* wq = (const float*)d_in[1];
  const float* wk = (const float*)d_in[2];
  const float* wv = (const float*)d_in[3];
  const float* qa = (const float*)d_in[4];
  const float* qb = (const float*)d_in[5];
  const float* ka = (const float*)d_in[6];
  const float* kb = (const float*)d_in[7];
  const float* va = (const float*)d_in[8];
  const float* vb = (const float*)d_in[9];

  // workspace layout: xb (67,108,864 B) | wb (3 * 33,554,432 B) = 160 MiB
  unsigned short* xb = (unsigned short*)d_ws;
  unsigned short* wb = xb + 8192UL * 4096UL;

  cvt_x_kernel<<<16384, 256, 0, stream>>>(x, xb, 8192L * 4096 / 8);
  fold_w_kernel<<<8192, 256, 0, stream>>>(wq, qa, qb, wb);
  fold_w_kernel<<<8192, 256, 0, stream>>>(wk, ka, kb, wb + 16777216UL);
  fold_w_kernel<<<8192, 256, 0, stream>>>(wv, va, vb, wb + 33554432UL);
  gemm_kernel<<<6144, 256, 0, stream>>>(xb, wb, (float*)d_out);
}

// Round 2
// 977.549 us; speedup vs baseline: 1.3740x; 1.3740x over previous
//
#include <hip/hip_runtime.h>

// ---------------------------------------------------------------------------
// LoRA QKV: out_p = x @ (W_p + B_p @ A_p)^T  for p in {q,k,v}
// M = 8192, N = 4096 per proj (x3), K = 4096.
// Fold LoRA into weights (exact), convert to bf16, one fused 3-proj GEMM
// using the 256x256 8-phase schedule (T2 swizzle + T3/T4 counted vmcnt + T5).
// ---------------------------------------------------------------------------

typedef __bf16 bf16x8 __attribute__((ext_vector_type(8)));
typedef float f32x4 __attribute__((ext_vector_type(4)));

#define GLL16(g, l)                                                        \
  __builtin_amdgcn_global_load_lds(                                        \
      (const __attribute__((address_space(1))) unsigned int*)(g),          \
      (__attribute__((address_space(3))) unsigned int*)(l), 16, 0, 0)

#define BAR()                                                              \
  {                                                                        \
    __builtin_amdgcn_sched_barrier(0);                                     \
    __builtin_amdgcn_s_barrier();                                          \
  }
#define WLG(n)                                                             \
  {                                                                        \
    asm volatile("s_waitcnt lgkmcnt(" #n ")" ::: "memory");                \
    __builtin_amdgcn_sched_barrier(0);                                     \
  }
#define WVM(n) asm volatile("s_waitcnt vmcnt(" #n ")" ::: "memory")

#define LDV(p) (*reinterpret_cast<const bf16x8*>(p))

// read 4 A-fragments (m = off0..off0+3) at k-swizzle swk
#define RD_A(dst, base, off0, swk)                                         \
  _Pragma("unroll") for (int mq = 0; mq < 4; ++mq) dst[(off0) + mq] =      \
      LDV((base) + ((off0) + mq) * 1024 + (swk));
#define RD_B(dst, base, swk)                                               \
  _Pragma("unroll") for (int nq = 0; nq < 4; ++nq) dst[nq] =               \
      LDV((base) + nq * 1024 + (swk));

// 16 MFMAs: one m-half (H=0/1) x all 4 n-frags, setprio-wrapped (T5)
#define MF16(AARR, BARR, H)                                                \
  {                                                                        \
    __builtin_amdgcn_s_setprio(1);                                         \
    _Pragma("unroll") for (int mm = 0; mm < 4; ++mm)                       \
        _Pragma("unroll") for (int nn = 0; nn < 4; ++nn) acc[(H)*4 + mm]   \
            [nn] = __builtin_amdgcn_mfma_f32_16x16x32_bf16(                \
                AARR[(H)*4 + mm], BARR[nn], acc[(H)*4 + mm][nn], 0, 0, 0); \
    __builtin_amdgcn_s_setprio(0);                                         \
  }

// stage one 8KB chunk (issue j) of A/B tile into LDS dbuf db, K-tile elem off ko
#define STG_A(db, j, ko)                                                   \
  GLL16(sa + (size_t)(j)*262144 + (ko),                                    \
        (char*)smem + (db)*65536 + (j)*8192 + tid * 16)
#define STG_B(db, j, ko)                                                   \
  GLL16(sb + (size_t)(j)*262144 + (ko),                                    \
        (char*)smem + (db)*65536 + 32768 + (j)*8192 + tid * 16)

__device__ __forceinline__ unsigned int f2b(float f) {
  unsigned int u = __builtin_bit_cast(unsigned int, f);
  u += 0x7FFFu + ((u >> 16) & 1u);
  return u >> 16;
}

// ---------------------------------------------------------------------------
// Kernel 1: convert x (fp32) -> bf16
// ---------------------------------------------------------------------------
__global__ void cvt_x_kernel(const float* __restrict__ x,
                             unsigned short* __restrict__ xb, long n8) {
  long i = (long)blockIdx.x * blockDim.x + threadIdx.x;
  if (i >= n8) return;
  const float4* xp = reinterpret_cast<const float4*>(x) + 2 * i;
  float4 v0 = xp[0];
  float4 v1 = xp[1];
  uint4 o;
  o.x = f2b(v0.x) | (f2b(v0.y) << 16);
  o.y = f2b(v0.z) | (f2b(v0.w) << 16);
  o.z = f2b(v1.x) | (f2b(v1.y) << 16);
  o.w = f2b(v1.z) | (f2b(v1.w) << 16);
  reinterpret_cast<uint4*>(xb)[i] = o;
}

// ---------------------------------------------------------------------------
// Kernel 2: W' = W + Bm @ A  (rank-16), fp32 accum, bf16 out
// ---------------------------------------------------------------------------
__global__ void fold_w_kernel(const float* __restrict__ W,
                              const float* __restrict__ Amat,
                              const float* __restrict__ Bmat,
                              unsigned short* __restrict__ Wb) {
  int gi = blockIdx.x * 256 + threadIdx.x;
  int d0 = (gi & 511) * 8;
  int h = gi >> 9;
  const float4* wp = reinterpret_cast<const float4*>(W + (size_t)h * 4096 + d0);
  float4 w0 = wp[0], w1 = wp[1];
  float acc[8] = {w0.x, w0.y, w0.z, w0.w, w1.x, w1.y, w1.z, w1.w};
  const float* bh = Bmat + h * 16;
#pragma unroll
  for (int r = 0; r < 16; ++r) {
    float bv = bh[r];
    const float4* ap =
        reinterpret_cast<const float4*>(Amat + (size_t)r * 4096 + d0);
    float4 a0 = ap[0], a1 = ap[1];
    acc[0] += bv * a0.x; acc[1] += bv * a0.y;
    acc[2] += bv * a0.z; acc[3] += bv * a0.w;
    acc[4] += bv * a1.x; acc[5] += bv * a1.y;
    acc[6] += bv * a1.z; acc[7] += bv * a1.w;
  }
  uint4 o;
  o.x = f2b(acc[0]) | (f2b(acc[1]) << 16);
  o.y = f2b(acc[2]) | (f2b(acc[3]) << 16);
  o.z = f2b(acc[4]) | (f2b(acc[5]) << 16);
  o.w = f2b(acc[6]) | (f2b(acc[7]) << 16);
  reinterpret_cast<uint4*>(Wb)[gi] = o;
}

// ---------------------------------------------------------------------------
// Kernel 3: 256x256-tile 8-phase GEMM.  C[M, N*3] = Xb[M,K] @ Wb[3][N,K]^T
//
// 512 threads = 8 waves (2M x 4N). BK=64 (2 x K32 substeps). LDS 128 KiB:
//   [A0 32K][B0 32K][A1 32K][B1 32K]  (double-buffered K-tiles)
// LDS swizzle: 16B slot s of row r holds global slot s^(r&7)  (T2; applied on
// the global SOURCE address, LDS written linearly by global_load_lds).
// Phases/iteration (2 K-tiles): reads front-loaded P1/P2 (P5/P6), stages
// spread P3..P8, vmcnt(4)@P4 / vmcnt(8)@P8 (T4, never 0 mid-loop), setprio
// around MFMA clusters (T5). lgkmcnt(0) before P2/P6 end-barriers => no
// in-flight LDS reads when any stage-write targets that buffer.
// ---------------------------------------------------------------------------
__global__ __launch_bounds__(512, 2) void gemm_kernel(
    const unsigned short* __restrict__ Xb,
    const unsigned short* __restrict__ Wb, float* __restrict__ out) {
  __shared__ unsigned short smem[65536];  // 128 KiB

  const int tid = threadIdx.x;
  const int lane = tid & 63;
  const int wid = tid >> 6;
  const int wm = wid >> 2;  // 0..1
  const int wn = wid & 3;   // 0..3

  int bid = blockIdx.x;  // 1536 = 3 proj * 32 brow * 16 bcol
  int swz = (bid & 7) * 192 + (bid >> 3);  // bijective XCD swizzle
  int p = swz >> 9;
  int r = swz & 511;
  int brow = r >> 4;  // 0..31
  int bcol = r & 15;  // 0..15

  const unsigned short* GA = Xb + (size_t)brow * 256 * 4096;
  const unsigned short* GB =
      Wb + (size_t)p * 16777216UL + (size_t)bcol * 256 * 4096;

  // staging: thread covers row j*64 + tid>>3, 16B slot tid&7; source slot
  // pre-swizzled so LDS[r][s] holds global[r][s^(r&7)]
  const int srow = tid >> 3;
  const int sslot = (tid & 7) ^ ((tid >> 3) & 7);
  const unsigned short* sa = GA + (size_t)srow * 4096 + sslot * 8;
  const unsigned short* sb = GB + (size_t)srow * 4096 + sslot * 8;

  // fragment-read bases (element units), swizzled k-slot offsets
  const int lrow = lane & 15;
  const int g = lane >> 4;  // 0..3
  const int swk0 = (g ^ (lane & 7)) * 8;
  const int swk1 = ((4 + g) ^ (lane & 7)) * 8;
  const __bf16* sm = (const __bf16*)smem;
  const __bf16* arA0 = sm + (wm * 128 + lrow) * 64;
  const __bf16* arB0 = sm + 16384 + (wn * 64 + lrow) * 64;
  const __bf16* arA1 = arA0 + 32768;
  const __bf16* arB1 = arB0 + 32768;

  f32x4 acc[8][4];
#pragma unroll
  for (int m = 0; m < 8; ++m)
#pragma unroll
    for (int n = 0; n < 4; ++n) acc[m][n] = {0.f, 0.f, 0.f, 0.f};

  // prologue: stage K-tiles 0 (buf0) and 1 (buf1)
#pragma unroll
  for (int j = 0; j < 4; ++j) {
    STG_A(0, j, 0);
    STG_B(0, j, 0);
  }
#pragma unroll
  for (int j = 0; j < 4; ++j) {
    STG_A(1, j, 64);
    STG_B(1, j, 64);
  }
  WVM(8);  // buf0 landed; buf1's 8 loads stay in flight
  BAR();

  for (int i = 0; i < 32; ++i) {
    const bool st = (i < 31);
    const size_t ko0 = (size_t)(2 * i + 2) * 64;
    const size_t ko1 = ko0 + 64;
    bf16x8 aK0[8], aK1[8], bK0[4], bK1[4];

    // ============ K-tile 2i (buffer 0) ============
    // P1: all k0 reads
    RD_A(aK0, arA0, 0, swk0);
    RD_B(bK0, arB0, swk0);
    RD_A(aK0, arA0, 4, swk0);
    BAR();
    WLG(4);
    MF16(aK0, bK0, 0);
    BAR();
    // P2: all k1 reads; drain ALL lds reads before end-barrier
    RD_A(aK1, arA0, 0, swk1);
    RD_B(bK1, arB0, swk1);
    RD_A(aK1, arA0, 4, swk1);
    BAR();
    WLG(0);
    MF16(aK0, bK0, 1);
    BAR();
    // P3: stage buf0 <- tile 2i+2 (chunk 0)
    if (st) {
      STG_A(0, 0, ko0);
      STG_B(0, 0, ko0);
    }
    BAR();
    MF16(aK1, bK1, 0);
    BAR();
    // P4: stage chunk 1; counted vmcnt drains prev-iter buf1 loads
    if (st) {
      STG_A(0, 1, ko0);
      STG_B(0, 1, ko0);
      WVM(4);
    } else {
      WVM(0);
    }
    BAR();
    MF16(aK1, bK1, 1);
    BAR();

    // ============ K-tile 2i+1 (buffer 1) ============
    // P5
    RD_A(aK0, arA1, 0, swk0);
    RD_B(bK0, arB1, swk0);
    RD_A(aK0, arA1, 4, swk0);
    if (st) {
      STG_A(0, 2, ko0);
      STG_B(0, 2, ko0);
    }
    BAR();
    WLG(4);
    MF16(aK0, bK0, 0);
    BAR();
    // P6
    RD_A(aK1, arA1, 0, swk1);
    RD_B(bK1, arB1, swk1);
    RD_A(aK1, arA1, 4, swk1);
    if (st) {
      STG_A(0, 3, ko0);
      STG_B(0, 3, ko0);
    }
    BAR();
    WLG(0);
    MF16(aK0, bK0, 1);
    BAR();
    // P7: stage buf1 <- tile 2i+3 (chunks 0,1)
    if (st) {
      STG_A(1, 0, ko1);
      STG_B(1, 0, ko1);
      STG_A(1, 1, ko1);
      STG_B(1, 1, ko1);
    }
    BAR();
    MF16(aK1, bK1, 0);
    BAR();
    // P8: stage chunks 2,3; counted vmcnt drains buf0's 8 loads
    if (st) {
      STG_A(1, 2, ko1);
      STG_B(1, 2, ko1);
      STG_A(1, 3, ko1);
      STG_B(1, 3, ko1);
      WVM(8);
    }
    BAR();
    MF16(aK1, bK1, 1);
    BAR();
  }

  // epilogue: C/D layout col = lane&15, row = (lane>>4)*4 + q
  float* Cp = out + (size_t)p * 33554432UL +
              ((size_t)(brow * 256 + wm * 128 + g * 4)) * 4096 +
              (bcol * 256 + wn * 64 + lrow);
#pragma unroll
  for (int m = 0; m < 8; ++m)
#pragma unroll
    for (int q = 0; q < 4; ++q) {
      float* rp = Cp + (size_t)(m * 16 + q) * 4096;
#pragma unroll
      for (int n = 0; n < 4; ++n) rp[n * 16] = acc[m][n][q];
    }
}

// ---------------------------------------------------------------------------
extern "C" void kernel_launch(void* const* d_in, const int* in_sizes, int n_in,
                              void* d_out, int out_size, void* d_ws,
                              size_t ws_size, hipStream_t stream) {
  const float* x = (const float*)d_in[0];
  const float* wq = (const float*)d_in[1];
  const float* wk = (const float*)d_in[2];
  const float* wv = (const float*)d_in[3];
  const float* qa = (const float*)d_in[4];
  const float* qb = (const float*)d_in[5];
  const float* ka = (const float*)d_in[6];
  const float* kb = (const float*)d_in[7];
  const float* va = (const float*)d_in[8];
  const float* vb = (const float*)d_in[9];

  unsigned short* xb = (unsigned short*)d_ws;           // 67 MB
  unsigned short* wb = xb + 8192UL * 4096UL;            // 100 MB

  cvt_x_kernel<<<16384, 256, 0, stream>>>(x, xb, 8192L * 4096 / 8);
  fold_w_kernel<<<8192, 256, 0, stream>>>(wq, qa, qb, wb);
  fold_w_kernel<<<8192, 256, 0, stream>>>(wk, ka, kb, wb + 16777216UL);
  fold_w_kernel<<<8192, 256, 0, stream>>>(wv, va, vb, wb + 33554432UL);
  gemm_kernel<<<1536, 512, 0, stream>>>(xb, wb, (float*)d_out);
}